// Round 1
// baseline (488.602 us; speedup 1.0000x reference)
//
#include <hip/hip_runtime.h>
#include <cstdint>
#include <cstddef>

#define B_   2
#define L_   4096
#define S_   77
#define TIP_ 16
#define C_   1280
#define CC_  768
#define H_   20

typedef unsigned short u16;
typedef unsigned int   u32;
typedef __attribute__((ext_vector_type(8))) short bf16x8;
typedef __attribute__((ext_vector_type(4))) float f32x4;

// f32 -> bf16 round-to-nearest-even (bit-level; avoids __hip_bfloat16 API variance)
__device__ __forceinline__ u16 f2bf(float x) {
  u32 u = __float_as_uint(x);
  u32 r = (u + 0x7fffu + ((u >> 16) & 1u)) >> 16;
  return (u16)r;
}

// async global->LDS, 16B per lane; lds base must be wave-uniform (CK cast pattern)
__device__ __forceinline__ void gload16(const u16* g, const u16* l) {
  __builtin_amdgcn_global_load_lds(
      (const __attribute__((address_space(1))) u32*)g,
      (__attribute__((address_space(3))) u32*)(uintptr_t)l, 16, 0, 0);
}

// ---------------- prep: flat f32->bf16 casts (X, enc, ip) ----------------
__global__ __launch_bounds__(256) void prep_cast(
    const float* __restrict__ X, const float* __restrict__ enc, const float* __restrict__ ip,
    u16* __restrict__ Xbf, u16* __restrict__ encbf, u16* __restrict__ ipbf) {
  const int nX = B_*L_*C_;     // 10485760
  const int nE = B_*S_*CC_;    // 118272
  const int nI = B_*TIP_*CC_;  // 24576
  const int total4 = (nX + nE + nI) >> 2;
  for (int i = blockIdx.x*256 + threadIdx.x; i < total4; i += gridDim.x*256) {
    int idx = i << 2;
    const float* src; u16* dst; int off;
    if (idx < nX)            { src = X;   dst = Xbf;   off = idx; }
    else if (idx < nX + nE)  { src = enc; dst = encbf; off = idx - nX; }
    else                     { src = ip;  dst = ipbf;  off = idx - nX - nE; }
    float4 v = *(const float4*)(src + off);
    ushort4 o;
    o.x = f2bf(v.x); o.y = f2bf(v.y); o.z = f2bf(v.z); o.w = f2bf(v.w);
    *(ushort4*)(dst + off) = o;
  }
}

// ---------------- transpose-cast: W [K][1280] f32 -> WT [1280][K] bf16 ----------------
__global__ __launch_bounds__(256) void transpose_cast(
    const float* __restrict__ Wq,  const float* __restrict__ Wk,   const float* __restrict__ Wv,
    const float* __restrict__ Wkip,const float* __restrict__ Wvip, const float* __restrict__ Wout,
    u16* __restrict__ WqT, u16* __restrict__ WkT, u16* __restrict__ WvT,
    u16* __restrict__ WkipT, u16* __restrict__ WvipT, u16* __restrict__ WoutT) {
  const int m = blockIdx.y;
  const float* src; u16* dst; int K;
  switch (m) {
    case 0: src = Wq;   dst = WqT;   K = C_;  break;
    case 1: src = Wk;   dst = WkT;   K = CC_; break;
    case 2: src = Wv;   dst = WvT;   K = CC_; break;
    case 3: src = Wkip; dst = WkipT; K = CC_; break;
    case 4: src = Wvip; dst = WvipT; K = CC_; break;
    default:src = Wout; dst = WoutT; K = C_;  break;
  }
  const int tileK = blockIdx.x / 40;       // N=1280 always -> 40 n-tiles
  const int tileN = blockIdx.x % 40;
  if (tileK >= (K >> 5)) return;
  __shared__ float tile[32][33];
  const int tx = threadIdx.x & 31, ty = threadIdx.x >> 5;  // 32 x 8
  const int k0 = tileK*32, n0 = tileN*32;
  #pragma unroll
  for (int r = 0; r < 32; r += 8)
    tile[ty + r][tx] = src[(size_t)(k0 + ty + r)*C_ + n0 + tx];
  __syncthreads();
  #pragma unroll
  for (int r = 0; r < 32; r += 8) {
    const int n = n0 + ty + r, k = k0 + tx;
    dst[(size_t)n*K + k] = f2bf(tile[tx][ty + r]);
  }
}

// ---------------- MFMA bf16 GEMM core: C[M,1280] = A[M,K] * BT[1280,K]^T ----------------
// 128x128 tile, BK=64, 256 threads (4 waves, 2x2), per-wave 64x64 via 4x4 16x16x32 frags.
__device__ __forceinline__ void gemm_core(
    const u16* __restrict__ A, int lda, int M,
    const u16* __restrict__ BT, int K,
    float* __restrict__ Cm,
    const float* __restrict__ bias, const float* __restrict__ resid, int epi,
    int mt, int nt) {
  __shared__ u16 As[128*64];
  __shared__ u16 Bs[128*64];
  const int tid  = threadIdx.x;
  const int lane = tid & 63, wave = tid >> 6;
  const int wm = wave >> 1, wn = wave & 1;
  const int lhi = lane >> 4, llo = lane & 15;

  f32x4 acc[4][4] = {};

  const int nkt = K >> 6;
  for (int kt = 0; kt < nkt; ++kt) {
    #pragma unroll
    for (int it = 0; it < 4; ++it) {
      const int chunk = it*256 + tid;       // 1024 chunks of 16B per 16KB tile
      const int r = chunk >> 3, c8 = chunk & 7;
      int row_g = mt*128 + r; row_g = (row_g < M) ? row_g : (M - 1);  // clamp: garbage rows never stored
      gload16(A  + (size_t)row_g*lda + kt*64 + c8*8, As + (size_t)(it*256 + wave*64)*8);
      const int nrow = nt*128 + r;          // N=1280 exact
      gload16(BT + (size_t)nrow*K  + kt*64 + c8*8, Bs + (size_t)(it*256 + wave*64)*8);
    }
    __syncthreads();   // drains vmcnt(0) for global_load_lds
    #pragma unroll
    for (int ks = 0; ks < 2; ++ks) {
      bf16x8 av[4], bv[4];
      #pragma unroll
      for (int mm = 0; mm < 4; ++mm)
        av[mm] = *(const bf16x8*)(As + (wm*64 + mm*16 + llo)*64 + ks*32 + lhi*8);
      #pragma unroll
      for (int nn = 0; nn < 4; ++nn)
        bv[nn] = *(const bf16x8*)(Bs + (wn*64 + nn*16 + llo)*64 + ks*32 + lhi*8);
      #pragma unroll
      for (int mm = 0; mm < 4; ++mm)
        #pragma unroll
        for (int nn = 0; nn < 4; ++nn)
          acc[mm][nn] = __builtin_amdgcn_mfma_f32_16x16x32_bf16(av[mm], bv[nn], acc[mm][nn], 0, 0, 0);
    }
    __syncthreads();   // protect LDS before next stage
  }

  #pragma unroll
  for (int mm = 0; mm < 4; ++mm) {
    #pragma unroll
    for (int nn = 0; nn < 4; ++nn) {
      const int row0 = mt*128 + wm*64 + mm*16 + lhi*4;
      const int col  = nt*128 + wn*64 + nn*16 + llo;
      #pragma unroll
      for (int r = 0; r < 4; ++r) {
        const int row = row0 + r;
        if (row < M) {
          float v = acc[mm][nn][r];
          if (epi) v += bias[col] + resid[(size_t)row*C_ + col];
          Cm[(size_t)row*C_ + col] = v;
        }
      }
    }
  }
}

template<int EPI>
__global__ __launch_bounds__(256) void gemm_bf16(
    const u16* __restrict__ A, int lda, int M, const u16* __restrict__ BT, int K,
    float* __restrict__ Cm, const float* __restrict__ bias, const float* __restrict__ resid) {
  gemm_core(A, lda, M, BT, K, Cm, bias, resid, EPI, blockIdx.x / 10, blockIdx.x % 10);
}

// z-batched tiny projections: K,V (M=154), K_ip,V_ip (M=32)
__global__ __launch_bounds__(256) void gemm_small(
    const u16* __restrict__ encbf, const u16* __restrict__ ipbf,
    const u16* __restrict__ WkT, const u16* __restrict__ WvT,
    const u16* __restrict__ WkipT, const u16* __restrict__ WvipT,
    float* __restrict__ Kf, float* __restrict__ Vf,
    float* __restrict__ Kipf, float* __restrict__ Vipf) {
  const int z = blockIdx.y;
  const u16* A; const u16* BT; float* Cm; int M;
  if      (z == 0) { A = encbf; BT = WkT;   Cm = Kf;   M = B_*S_; }
  else if (z == 1) { A = encbf; BT = WvT;   Cm = Vf;   M = B_*S_; }
  else if (z == 2) { A = ipbf;  BT = WkipT; Cm = Kipf; M = B_*TIP_; }
  else             { A = ipbf;  BT = WvipT; Cm = Vipf; M = B_*TIP_; }
  gemm_core(A, CC_, M, BT, CC_, Cm, nullptr, nullptr, 0, blockIdx.x / 10, blockIdx.x % 10);
}

// ---------------- fused biased-softmax attention + IP stream, f32, thread-per-row ----------------
__global__ __launch_bounds__(256) void attn_kernel(
    const float* __restrict__ Qf, const float* __restrict__ Kf, const float* __restrict__ Vf,
    const float* __restrict__ Kipf, const float* __restrict__ Vipf,
    const float* __restrict__ region, const float* __restrict__ sigma,
    u16* __restrict__ attnbf) {
  __shared__ float Kl[S_][64];
  __shared__ float Vl[S_][64];
  __shared__ float Kipl[TIP_][64];
  __shared__ float Vipl[TIP_][64];
  const int b = blockIdx.z, h = blockIdx.y, tid = threadIdx.x;

  for (int i = tid; i < S_*64; i += 256) {
    const int s = i >> 6, d = i & 63;
    const size_t off = (size_t)(b*S_ + s)*C_ + h*64 + d;
    Kl[s][d] = Kf[off];
    Vl[s][d] = Vf[off];
  }
  for (int i = tid; i < TIP_*64; i += 256) {
    const int s = i >> 6, d = i & 63;
    const size_t off = (size_t)(b*TIP_ + s)*C_ + h*64 + d;
    Kipl[s][d] = Kipf[off];
    Vipl[s][d] = Vipf[off];
  }
  __syncthreads();

  const int l = blockIdx.x*256 + tid;
  const float* qrow = Qf + (size_t)(b*L_ + l)*C_ + h*64;
  const float sigscale = sigma[0] * 0.3f;   // REGION_WEIGHT
  const float scale = 0.125f;               // 1/sqrt(64)

  float sc[S_];
  float scip[TIP_];
  #pragma unroll
  for (int s = 0; s < S_; ++s) sc[s] = 0.f;
  #pragma unroll
  for (int t = 0; t < TIP_; ++t) scip[t] = 0.f;

  // scores (both streams share the q4 read)
  #pragma unroll 1
  for (int d4 = 0; d4 < 16; ++d4) {
    const float4 q4 = *(const float4*)(qrow + d4*4);
    #pragma unroll
    for (int s = 0; s < S_; ++s) {
      const float4 k4 = *(const float4*)(&Kl[s][d4*4]);   // wave-broadcast LDS read
      sc[s] = fmaf(q4.x, k4.x, fmaf(q4.y, k4.y, fmaf(q4.z, k4.z, fmaf(q4.w, k4.w, sc[s]))));
    }
    #pragma unroll
    for (int t = 0; t < TIP_; ++t) {
      const float4 k4 = *(const float4*)(&Kipl[t][d4*4]);
      scip[t] = fmaf(q4.x, k4.x, fmaf(q4.y, k4.y, fmaf(q4.z, k4.z, fmaf(q4.w, k4.w, scip[t]))));
    }
  }

  // main stream: scale + region bias, softmax (normalized into sc)
  const float* rrow = region + (size_t)(b*L_ + l)*S_;
  float mx = -1e30f;
  #pragma unroll
  for (int s = 0; s < S_; ++s) {
    sc[s] = fmaf(sc[s], scale, rrow[s] * sigscale);
    mx = fmaxf(mx, sc[s]);
  }
  float sum = 0.f;
  #pragma unroll
  for (int s = 0; s < S_; ++s) { sc[s] = __expf(sc[s] - mx); sum += sc[s]; }
  const float inv = 1.f / sum;
  #pragma unroll
  for (int s = 0; s < S_; ++s) sc[s] *= inv;

  // ip stream softmax (no bias), IP_SCALE = 1.0
  float mxi = -1e30f;
  #pragma unroll
  for (int t = 0; t < TIP_; ++t) { scip[t] *= scale; mxi = fmaxf(mxi, scip[t]); }
  float sumi = 0.f;
  #pragma unroll
  for (int t = 0; t < TIP_; ++t) { scip[t] = __expf(scip[t] - mxi); sumi += scip[t]; }
  const float invi = 1.f / sumi;
  #pragma unroll
  for (int t = 0; t < TIP_; ++t) scip[t] *= invi;

  // combined PV, write bf16
  u16* orow = attnbf + (size_t)(b*L_ + l)*C_ + h*64;
  #pragma unroll 1
  for (int d4 = 0; d4 < 16; ++d4) {
    float ax = 0.f, ay = 0.f, az = 0.f, aw = 0.f;
    #pragma unroll
    for (int s = 0; s < S_; ++s) {
      const float4 v4 = *(const float4*)(&Vl[s][d4*4]);
      ax = fmaf(sc[s], v4.x, ax); ay = fmaf(sc[s], v4.y, ay);
      az = fmaf(sc[s], v4.z, az); aw = fmaf(sc[s], v4.w, aw);
    }
    #pragma unroll
    for (int t = 0; t < TIP_; ++t) {
      const float4 v4 = *(const float4*)(&Vipl[t][d4*4]);
      ax = fmaf(scip[t], v4.x, ax); ay = fmaf(scip[t], v4.y, ay);
      az = fmaf(scip[t], v4.z, az); aw = fmaf(scip[t], v4.w, aw);
    }
    ushort4 o;
    o.x = f2bf(ax); o.y = f2bf(ay); o.z = f2bf(az); o.w = f2bf(aw);
    *(ushort4*)(orow + d4*4) = o;
  }
}

// ---------------- launcher ----------------
extern "C" void kernel_launch(void* const* d_in, const int* in_sizes, int n_in,
                              void* d_out, int out_size, void* d_ws, size_t ws_size,
                              hipStream_t stream) {
  const float* hidden = (const float*)d_in[0];
  const float* enc    = (const float*)d_in[1];
  const float* ip     = (const float*)d_in[2];
  const float* region = (const float*)d_in[3];
  const float* sigma  = (const float*)d_in[4];
  const float* Wq     = (const float*)d_in[5];
  const float* Wk     = (const float*)d_in[6];
  const float* Wv     = (const float*)d_in[7];
  const float* Wkip   = (const float*)d_in[8];
  const float* Wvip   = (const float*)d_in[9];
  const float* Wout   = (const float*)d_in[10];
  const float* bout   = (const float*)d_in[11];

  char* base = (char*)d_ws;
  size_t off = 0;
  auto carve = [&](size_t bytes) -> void* {
    void* r = base + off;
    off += (bytes + 255) & ~(size_t)255;
    return r;
  };
  u16*   Xbf    = (u16*)  carve((size_t)B_*L_*C_*2);
  u16*   encbf  = (u16*)  carve((size_t)B_*S_*CC_*2);
  u16*   ipbf   = (u16*)  carve((size_t)B_*TIP_*CC_*2);
  u16*   WqT    = (u16*)  carve((size_t)C_*C_*2);
  u16*   WkT    = (u16*)  carve((size_t)C_*CC_*2);
  u16*   WvT    = (u16*)  carve((size_t)C_*CC_*2);
  u16*   WkipT  = (u16*)  carve((size_t)C_*CC_*2);
  u16*   WvipT  = (u16*)  carve((size_t)C_*CC_*2);
  u16*   WoutT  = (u16*)  carve((size_t)C_*C_*2);
  float* Qf     = (float*)carve((size_t)B_*L_*C_*4);
  float* Kf     = (float*)carve((size_t)B_*S_*C_*4);
  float* Vf     = (float*)carve((size_t)B_*S_*C_*4);
  float* Kipf   = (float*)carve((size_t)B_*TIP_*C_*4);
  float* Vipf   = (float*)carve((size_t)B_*TIP_*C_*4);
  u16*   attnbf = (u16*)  carve((size_t)B_*L_*C_*2);
  (void)ws_size; (void)in_sizes; (void)n_in; (void)out_size;

  prep_cast<<<2048, 256, 0, stream>>>(hidden, enc, ip, Xbf, encbf, ipbf);
  transpose_cast<<<dim3(1600, 6), 256, 0, stream>>>(Wq, Wk, Wv, Wkip, Wvip, Wout,
                                                    WqT, WkT, WvT, WkipT, WvipT, WoutT);
  // Q = X @ Wq   [8192,1280] x [1280,1280]
  gemm_bf16<0><<<dim3(64*10), 256, 0, stream>>>(Xbf, C_, B_*L_, WqT, C_, Qf, nullptr, nullptr);
  // K,V,K_ip,V_ip projections
  gemm_small<<<dim3(2*10, 4), 256, 0, stream>>>(encbf, ipbf, WkT, WvT, WkipT, WvipT,
                                                Kf, Vf, Kipf, Vipf);
  // fused attention (both streams) -> bf16 [8192,1280]
  attn_kernel<<<dim3(L_/256, H_, B_), 256, 0, stream>>>(Qf, Kf, Vf, Kipf, Vipf,
                                                        region, sigma, attnbf);
  // out = attn @ Wout + b_out + residual
  gemm_bf16<1><<<dim3(64*10), 256, 0, stream>>>(attnbf, C_, B_*L_, WoutT, C_,
                                                (float*)d_out, bout, hidden);
}

// Round 2
// 238.910 us; speedup vs baseline: 2.0451x; 2.0451x over previous
//
#include <hip/hip_runtime.h>
#include <cstdint>
#include <cstddef>

#define B_   2
#define L_   4096
#define S_   77
#define TIP_ 16
#define C_   1280
#define CC_  768
#define H_   20

typedef unsigned short u16;
typedef unsigned int   u32;
typedef __attribute__((ext_vector_type(8))) short bf16x8;
typedef __attribute__((ext_vector_type(8))) unsigned short u16x8;
typedef __attribute__((ext_vector_type(4))) float f32x4;

// f32 -> bf16 round-to-nearest-even
__device__ __forceinline__ u16 f2bf(float x) {
  u32 u = __float_as_uint(x);
  u32 r = (u + 0x7fffu + ((u >> 16) & 1u)) >> 16;
  return (u16)r;
}

// async global->LDS, 16B per lane (dest = wave-uniform base + lane*16)
__device__ __forceinline__ void gload16(const u16* g, const u16* l) {
  __builtin_amdgcn_global_load_lds(
      (const __attribute__((address_space(1))) u32*)g,
      (__attribute__((address_space(3))) u32*)(uintptr_t)l, 16, 0, 0);
}

// ---------------- prep: flat f32->bf16 casts (X, enc, ip) ----------------
__global__ __launch_bounds__(256) void prep_cast(
    const float* __restrict__ X, const float* __restrict__ enc, const float* __restrict__ ip,
    u16* __restrict__ Xbf, u16* __restrict__ encbf, u16* __restrict__ ipbf) {
  const int nX = B_*L_*C_;
  const int nE = B_*S_*CC_;
  const int nI = B_*TIP_*CC_;
  const int total4 = (nX + nE + nI) >> 2;
  for (int i = blockIdx.x*256 + threadIdx.x; i < total4; i += gridDim.x*256) {
    int idx = i << 2;
    const float* src; u16* dst; int off;
    if (idx < nX)            { src = X;   dst = Xbf;   off = idx; }
    else if (idx < nX + nE)  { src = enc; dst = encbf; off = idx - nX; }
    else                     { src = ip;  dst = ipbf;  off = idx - nX - nE; }
    float4 v = *(const float4*)(src + off);
    ushort4 o;
    o.x = f2bf(v.x); o.y = f2bf(v.y); o.z = f2bf(v.z); o.w = f2bf(v.w);
    *(ushort4*)(dst + off) = o;
  }
}

// ---------------- transpose-cast: W [K][1280] f32 -> WT [1280][K] bf16 ----------------
__global__ __launch_bounds__(256) void transpose_cast(
    const float* __restrict__ Wq,  const float* __restrict__ Wk,   const float* __restrict__ Wv,
    const float* __restrict__ Wkip,const float* __restrict__ Wvip, const float* __restrict__ Wout,
    u16* __restrict__ WqT, u16* __restrict__ WkT, u16* __restrict__ WvT,
    u16* __restrict__ WkipT, u16* __restrict__ WvipT, u16* __restrict__ WoutT) {
  const int m = blockIdx.y;
  const float* src; u16* dst; int K;
  switch (m) {
    case 0: src = Wq;   dst = WqT;   K = C_;  break;
    case 1: src = Wk;   dst = WkT;   K = CC_; break;
    case 2: src = Wv;   dst = WvT;   K = CC_; break;
    case 3: src = Wkip; dst = WkipT; K = CC_; break;
    case 4: src = Wvip; dst = WvipT; K = CC_; break;
    default:src = Wout; dst = WoutT; K = C_;  break;
  }
  const int tileK = blockIdx.x / 40;
  const int tileN = blockIdx.x % 40;
  if (tileK >= (K >> 5)) return;
  __shared__ float tile[32][33];
  const int tx = threadIdx.x & 31, ty = threadIdx.x >> 5;
  const int k0 = tileK*32, n0 = tileN*32;
  #pragma unroll
  for (int r = 0; r < 32; r += 8)
    tile[ty + r][tx] = src[(size_t)(k0 + ty + r)*C_ + n0 + tx];
  __syncthreads();
  #pragma unroll
  for (int r = 0; r < 32; r += 8) {
    const int n = n0 + ty + r, k = k0 + tx;
    dst[(size_t)n*K + k] = f2bf(tile[tx][ty + r]);
  }
}

// ---------------- MFMA bf16 GEMM core ----------------
// MODE 1: f32 out + bias + residual.  MODE 2: bf16 (u16) out.
template<int MODE, typename OutT>
__device__ __forceinline__ void gemm_core(
    const u16* __restrict__ A, int lda, int M,
    const u16* __restrict__ BT, int K,
    OutT* __restrict__ Cm,
    const float* __restrict__ bias, const float* __restrict__ resid,
    int mt, int nt) {
  __shared__ u16 As[128*64];
  __shared__ u16 Bs[128*64];
  const int tid  = threadIdx.x;
  const int lane = tid & 63, wave = tid >> 6;
  const int wm = wave >> 1, wn = wave & 1;
  const int lhi = lane >> 4, llo = lane & 15;

  f32x4 acc[4][4] = {};

  const int nkt = K >> 6;
  for (int kt = 0; kt < nkt; ++kt) {
    #pragma unroll
    for (int it = 0; it < 4; ++it) {
      const int chunk = it*256 + tid;
      const int r = chunk >> 3, c8 = chunk & 7;
      int row_g = mt*128 + r; row_g = (row_g < M) ? row_g : (M - 1);
      gload16(A  + (size_t)row_g*lda + kt*64 + c8*8, As + (size_t)(it*256 + wave*64)*8);
      const int nrow = nt*128 + r;
      gload16(BT + (size_t)nrow*K  + kt*64 + c8*8, Bs + (size_t)(it*256 + wave*64)*8);
    }
    __syncthreads();
    #pragma unroll
    for (int ks = 0; ks < 2; ++ks) {
      bf16x8 av[4], bv[4];
      #pragma unroll
      for (int mm = 0; mm < 4; ++mm)
        av[mm] = *(const bf16x8*)(As + (wm*64 + mm*16 + llo)*64 + ks*32 + lhi*8);
      #pragma unroll
      for (int nn = 0; nn < 4; ++nn)
        bv[nn] = *(const bf16x8*)(Bs + (wn*64 + nn*16 + llo)*64 + ks*32 + lhi*8);
      #pragma unroll
      for (int mm = 0; mm < 4; ++mm)
        #pragma unroll
        for (int nn = 0; nn < 4; ++nn)
          acc[mm][nn] = __builtin_amdgcn_mfma_f32_16x16x32_bf16(av[mm], bv[nn], acc[mm][nn], 0, 0, 0);
    }
    __syncthreads();
  }

  #pragma unroll
  for (int mm = 0; mm < 4; ++mm) {
    #pragma unroll
    for (int nn = 0; nn < 4; ++nn) {
      const int row0 = mt*128 + wm*64 + mm*16 + lhi*4;
      const int col  = nt*128 + wn*64 + nn*16 + llo;
      #pragma unroll
      for (int r = 0; r < 4; ++r) {
        const int row = row0 + r;
        if (row < M) {
          float v = acc[mm][nn][r];
          if constexpr (MODE == 1) {
            v += bias[col] + resid[(size_t)row*C_ + col];
            Cm[(size_t)row*C_ + col] = v;
          } else {
            Cm[(size_t)row*C_ + col] = f2bf(v);
          }
        }
      }
    }
  }
}

template<int MODE, typename OutT>
__global__ __launch_bounds__(256) void gemm_bf16(
    const u16* __restrict__ A, int lda, int M, const u16* __restrict__ BT, int K,
    OutT* __restrict__ Cm, const float* __restrict__ bias, const float* __restrict__ resid) {
  gemm_core<MODE, OutT>(A, lda, M, BT, K, Cm, bias, resid, blockIdx.x / 10, blockIdx.x % 10);
}

// z-batched tiny projections -> bf16 outputs
__global__ __launch_bounds__(256) void gemm_small(
    const u16* __restrict__ encbf, const u16* __restrict__ ipbf,
    const u16* __restrict__ WkT, const u16* __restrict__ WvT,
    const u16* __restrict__ WkipT, const u16* __restrict__ WvipT,
    u16* __restrict__ Kbf, u16* __restrict__ Vbf,
    u16* __restrict__ Kipbf, u16* __restrict__ Vipbf) {
  const int z = blockIdx.y;
  const u16* A; const u16* BT; u16* Cm; int M;
  if      (z == 0) { A = encbf; BT = WkT;   Cm = Kbf;   M = B_*S_; }
  else if (z == 1) { A = encbf; BT = WvT;   Cm = Vbf;   M = B_*S_; }
  else if (z == 2) { A = ipbf;  BT = WkipT; Cm = Kipbf; M = B_*TIP_; }
  else             { A = ipbf;  BT = WvipT; Cm = Vipbf; M = B_*TIP_; }
  gemm_core<2, u16>(A, CC_, M, BT, CC_, Cm, nullptr, nullptr, blockIdx.x / 10, blockIdx.x % 10);
}

// ---------------- MFMA fused attention ----------------
// Unified key space of 96: [0,77)=text keys, [77,80)=zero pad, [80,96)=IP keys.
// Per block: one (b,h), 128 query rows; 4 waves x 32 rows.
// QK^T via mfma 16x16x32 (A=Q frags from global bf16, B=K frags from LDS),
// two row-softmaxes (16-lane butterfly), P->LDS bf16, combined PV via mfma.
#define KSP   96          // padded key space
#define KLD   72          // K LDS stride (2-way bank alias only)
#define PLD   104         // P / Vt LDS stride (2-way bank alias only)
__global__ __launch_bounds__(256) void attn_mfma(
    const u16* __restrict__ Qbf,
    const u16* __restrict__ Kbf,  const u16* __restrict__ Vbf,
    const u16* __restrict__ Kipbf, const u16* __restrict__ Vipbf,
    const float* __restrict__ region, const float* __restrict__ sigma,
    u16* __restrict__ attnbf) {
  __shared__ u16 Kl[KSP*KLD];       // K rows (keys) x 64 dims, stride 72
  __shared__ u16 Vt[64*PLD];        // V transposed: [d][s], stride 104
  __shared__ u16 Pl[4*32*PLD];      // per-wave P tiles [32 rows][96 cols], stride 104
  const int b = blockIdx.z, h = blockIdx.y;
  const int tid = threadIdx.x, lane = tid & 63, wave = tid >> 6;
  const int llo = lane & 15, lhi = lane >> 4;

  // ---- stage K (rows of unified key space), 16B chunks ----
  for (int i = tid; i < KSP*8; i += 256) {
    const int r = i >> 3, c8 = i & 7;
    u16x8 val = {0,0,0,0,0,0,0,0};
    if (r < S_)
      val = *(const u16x8*)(Kbf + ((size_t)(b*S_ + r))*C_ + h*64 + c8*8);
    else if (r >= 80)
      val = *(const u16x8*)(Kipbf + ((size_t)(b*TIP_ + r - 80))*C_ + h*64 + c8*8);
    *(u16x8*)(Kl + r*KLD + c8*8) = val;
  }
  // ---- stage V transposed: Vt[d][s] ----
  for (int i = tid; i < KSP*64; i += 256) {
    const int s = i >> 6, d = i & 63;
    u16 val = 0;
    if (s < S_)       val = Vbf[((size_t)(b*S_ + s))*C_ + h*64 + d];
    else if (s >= 80) val = Vipbf[((size_t)(b*TIP_ + s - 80))*C_ + h*64 + d];
    Vt[d*PLD + s] = val;
  }
  __syncthreads();

  const int row0 = blockIdx.x*128 + wave*32;

  // ---- Q fragments straight from global (bf16) ----
  bf16x8 av[2][2];
  #pragma unroll
  for (int mm = 0; mm < 2; ++mm)
    #pragma unroll
    for (int ks = 0; ks < 2; ++ks)
      av[mm][ks] = *(const bf16x8*)(Qbf + ((size_t)(b*L_ + row0 + mm*16 + llo))*C_ + h*64 + ks*32 + lhi*8);

  // ---- QK^T ----
  f32x4 acc[2][6] = {};
  #pragma unroll
  for (int ks = 0; ks < 2; ++ks) {
    bf16x8 bv[6];
    #pragma unroll
    for (int nn = 0; nn < 6; ++nn)
      bv[nn] = *(const bf16x8*)(Kl + (nn*16 + llo)*KLD + ks*32 + lhi*8);
    #pragma unroll
    for (int mm = 0; mm < 2; ++mm)
      #pragma unroll
      for (int nn = 0; nn < 6; ++nn)
        acc[mm][nn] = __builtin_amdgcn_mfma_f32_16x16x32_bf16(av[mm][ks], bv[nn], acc[mm][nn], 0, 0, 0);
  }

  // ---- softmax (per row; rows live in 16-lane llo groups) + P -> LDS ----
  const float sigscale = sigma[0] * 0.3f;   // REGION_WEIGHT
  const float scale = 0.125f;               // 1/sqrt(64)
  u16* Pw = Pl + wave*32*PLD;

  #pragma unroll
  for (int mm = 0; mm < 2; ++mm) {
    const int rowbase = b*L_ + row0 + mm*16 + lhi*4;   // + r
    // main stream: cols 0..76 across nn=0..4
    float sc[5][4];
    float mx[4] = {-1e30f, -1e30f, -1e30f, -1e30f};
    #pragma unroll
    for (int nn = 0; nn < 5; ++nn) {
      const int col = nn*16 + llo;
      #pragma unroll
      for (int r = 0; r < 4; ++r) {
        float v = -1e30f;
        if (col < S_) {
          const float bias = region[((size_t)(rowbase + r))*S_ + col] * sigscale;
          v = fmaf(acc[mm][nn][r], scale, bias);
        }
        sc[nn][r] = v;
        mx[r] = fmaxf(mx[r], v);
      }
    }
    #pragma unroll
    for (int st = 1; st < 16; st <<= 1)
      #pragma unroll
      for (int r = 0; r < 4; ++r)
        mx[r] = fmaxf(mx[r], __shfl_xor(mx[r], st));
    float sum[4] = {0.f, 0.f, 0.f, 0.f};
    #pragma unroll
    for (int nn = 0; nn < 5; ++nn)
      #pragma unroll
      for (int r = 0; r < 4; ++r) {
        const float e = __expf(sc[nn][r] - mx[r]);   // masked cols underflow to 0
        sc[nn][r] = e; sum[r] += e;
      }
    #pragma unroll
    for (int st = 1; st < 16; st <<= 1)
      #pragma unroll
      for (int r = 0; r < 4; ++r)
        sum[r] += __shfl_xor(sum[r], st);
    float inv[4];
    #pragma unroll
    for (int r = 0; r < 4; ++r) inv[r] = 1.f / sum[r];

    // ip stream: nn=5 (cols 80..95), plain softmax
    float ipe[4], mi[4], sumi[4];
    #pragma unroll
    for (int r = 0; r < 4; ++r) { ipe[r] = acc[mm][5][r] * scale; mi[r] = ipe[r]; }
    #pragma unroll
    for (int st = 1; st < 16; st <<= 1)
      #pragma unroll
      for (int r = 0; r < 4; ++r)
        mi[r] = fmaxf(mi[r], __shfl_xor(mi[r], st));
    #pragma unroll
    for (int r = 0; r < 4; ++r) { ipe[r] = __expf(ipe[r] - mi[r]); sumi[r] = ipe[r]; }
    #pragma unroll
    for (int st = 1; st < 16; st <<= 1)
      #pragma unroll
      for (int r = 0; r < 4; ++r)
        sumi[r] += __shfl_xor(sumi[r], st);

    // write P (bf16) into per-wave LDS tile
    #pragma unroll
    for (int nn = 0; nn < 5; ++nn)
      #pragma unroll
      for (int r = 0; r < 4; ++r)
        Pw[(mm*16 + lhi*4 + r)*PLD + nn*16 + llo] = f2bf(sc[nn][r] * inv[r]);
    #pragma unroll
    for (int r = 0; r < 4; ++r)
      Pw[(mm*16 + lhi*4 + r)*PLD + 80 + llo] = f2bf(ipe[r] / sumi[r]);
  }

  // ---- PV (combined text+IP since IP_SCALE=1) ----
  f32x4 oacc[2][4] = {};
  #pragma unroll
  for (int ks = 0; ks < 3; ++ks) {         // K-dim 96 = 3 x 32
    bf16x8 pa[2], vv[4];
    #pragma unroll
    for (int mm = 0; mm < 2; ++mm)
      pa[mm] = *(const bf16x8*)(Pw + (mm*16 + llo)*PLD + ks*32 + lhi*8);
    #pragma unroll
    for (int nn = 0; nn < 4; ++nn)
      vv[nn] = *(const bf16x8*)(Vt + (nn*16 + llo)*PLD + ks*32 + lhi*8);
    #pragma unroll
    for (int mm = 0; mm < 2; ++mm)
      #pragma unroll
      for (int nn = 0; nn < 4; ++nn)
        oacc[mm][nn] = __builtin_amdgcn_mfma_f32_16x16x32_bf16(pa[mm], vv[nn], oacc[mm][nn], 0, 0, 0);
  }

  // ---- store attn output (bf16) ----
  #pragma unroll
  for (int mm = 0; mm < 2; ++mm)
    #pragma unroll
    for (int nn = 0; nn < 4; ++nn)
      #pragma unroll
      for (int r = 0; r < 4; ++r) {
        const int grow = row0 + mm*16 + lhi*4 + r;
        attnbf[((size_t)(b*L_ + grow))*C_ + h*64 + nn*16 + llo] = f2bf(oacc[mm][nn][r]);
      }
}

// ---------------- launcher ----------------
extern "C" void kernel_launch(void* const* d_in, const int* in_sizes, int n_in,
                              void* d_out, int out_size, void* d_ws, size_t ws_size,
                              hipStream_t stream) {
  const float* hidden = (const float*)d_in[0];
  const float* enc    = (const float*)d_in[1];
  const float* ip     = (const float*)d_in[2];
  const float* region = (const float*)d_in[3];
  const float* sigma  = (const float*)d_in[4];
  const float* Wq     = (const float*)d_in[5];
  const float* Wk     = (const float*)d_in[6];
  const float* Wv     = (const float*)d_in[7];
  const float* Wkip   = (const float*)d_in[8];
  const float* Wvip   = (const float*)d_in[9];
  const float* Wout   = (const float*)d_in[10];
  const float* bout   = (const float*)d_in[11];

  char* base = (char*)d_ws;
  size_t off = 0;
  auto carve = [&](size_t bytes) -> void* {
    void* r = base + off;
    off += (bytes + 255) & ~(size_t)255;
    return r;
  };
  u16* Xbf    = (u16*)carve((size_t)B_*L_*C_*2);
  u16* encbf  = (u16*)carve((size_t)B_*S_*CC_*2);
  u16* ipbf   = (u16*)carve((size_t)B_*TIP_*CC_*2);
  u16* WqT    = (u16*)carve((size_t)C_*C_*2);
  u16* WkT    = (u16*)carve((size_t)C_*CC_*2);
  u16* WvT    = (u16*)carve((size_t)C_*CC_*2);
  u16* WkipT  = (u16*)carve((size_t)C_*CC_*2);
  u16* WvipT  = (u16*)carve((size_t)C_*CC_*2);
  u16* WoutT  = (u16*)carve((size_t)C_*C_*2);
  u16* Qbf    = (u16*)carve((size_t)B_*L_*C_*2);
  u16* Kbf    = (u16*)carve((size_t)B_*S_*C_*2);
  u16* Vbf    = (u16*)carve((size_t)B_*S_*C_*2);
  u16* Kipbf  = (u16*)carve((size_t)B_*TIP_*C_*2);
  u16* Vipbf  = (u16*)carve((size_t)B_*TIP_*C_*2);
  u16* attnbf = (u16*)carve((size_t)B_*L_*C_*2);
  (void)ws_size; (void)in_sizes; (void)n_in; (void)out_size;

  prep_cast<<<2048, 256, 0, stream>>>(hidden, enc, ip, Xbf, encbf, ipbf);
  transpose_cast<<<dim3(1600, 6), 256, 0, stream>>>(Wq, Wk, Wv, Wkip, Wvip, Wout,
                                                    WqT, WkT, WvT, WkipT, WvipT, WoutT);
  // Q = X @ Wq -> bf16
  gemm_bf16<2, u16><<<dim3(64*10), 256, 0, stream>>>(Xbf, C_, B_*L_, WqT, C_, Qbf, nullptr, nullptr);
  // K,V,K_ip,V_ip projections -> bf16
  gemm_small<<<dim3(2*10, 4), 256, 0, stream>>>(encbf, ipbf, WkT, WvT, WkipT, WvipT,
                                                Kbf, Vbf, Kipbf, Vipbf);
  // fused MFMA attention (text + IP) -> bf16
  attn_mfma<<<dim3(L_/128, H_, B_), 256, 0, stream>>>(Qbf, Kbf, Vbf, Kipbf, Vipbf,
                                                      region, sigma, attnbf);
  // out = attn @ Wout + b_out + residual
  gemm_bf16<1, float><<<dim3(64*10), 256, 0, stream>>>(attnbf, C_, B_*L_, WoutT, C_,
                                                       (float*)d_out, bout, hidden);
}

// Round 3
// 179.657 us; speedup vs baseline: 2.7196x; 1.3298x over previous
//
#include <hip/hip_runtime.h>
#include <cstdint>
#include <cstddef>

#define B_   2
#define L_   4096
#define S_   77
#define TIP_ 16
#define C_   1280
#define CC_  768
#define H_   20

typedef unsigned short u16;
typedef unsigned int   u32;
typedef __attribute__((ext_vector_type(8))) short bf16x8;
typedef __attribute__((ext_vector_type(8))) unsigned short u16x8;
typedef __attribute__((ext_vector_type(4))) float f32x4;

// f32 -> bf16 round-to-nearest-even
__device__ __forceinline__ u16 f2bf(float x) {
  u32 u = __float_as_uint(x);
  u32 r = (u + 0x7fffu + ((u >> 16) & 1u)) >> 16;
  return (u16)r;
}

// async global->LDS, 16B per lane (dest = wave-uniform base + lane*16)
__device__ __forceinline__ void gload16(const u16* g, const u16* l) {
  __builtin_amdgcn_global_load_lds(
      (const __attribute__((address_space(1))) u32*)g,
      (__attribute__((address_space(3))) u32*)(uintptr_t)l, 16, 0, 0);
}

// ---------------- prep: flat f32->bf16 casts (X, enc, ip) ----------------
__global__ __launch_bounds__(256) void prep_cast(
    const float* __restrict__ X, const float* __restrict__ enc, const float* __restrict__ ip,
    u16* __restrict__ Xbf, u16* __restrict__ encbf, u16* __restrict__ ipbf) {
  const int nX = B_*L_*C_;
  const int nE = B_*S_*CC_;
  const int nI = B_*TIP_*CC_;
  const int total4 = (nX + nE + nI) >> 2;
  for (int i = blockIdx.x*256 + threadIdx.x; i < total4; i += gridDim.x*256) {
    int idx = i << 2;
    const float* src; u16* dst; int off;
    if (idx < nX)            { src = X;   dst = Xbf;   off = idx; }
    else if (idx < nX + nE)  { src = enc; dst = encbf; off = idx - nX; }
    else                     { src = ip;  dst = ipbf;  off = idx - nX - nE; }
    float4 v = *(const float4*)(src + off);
    ushort4 o;
    o.x = f2bf(v.x); o.y = f2bf(v.y); o.z = f2bf(v.z); o.w = f2bf(v.w);
    *(ushort4*)(dst + off) = o;
  }
}

// ---------------- transpose-cast: W [K][1280] f32 -> WT [1280][K] bf16 ----------------
__global__ __launch_bounds__(256) void transpose_cast(
    const float* __restrict__ Wq,  const float* __restrict__ Wk,   const float* __restrict__ Wv,
    const float* __restrict__ Wkip,const float* __restrict__ Wvip, const float* __restrict__ Wout,
    u16* __restrict__ WqT, u16* __restrict__ WkT, u16* __restrict__ WvT,
    u16* __restrict__ WkipT, u16* __restrict__ WvipT, u16* __restrict__ WoutT) {
  const int m = blockIdx.y;
  const float* src; u16* dst; int K;
  switch (m) {
    case 0: src = Wq;   dst = WqT;   K = C_;  break;
    case 1: src = Wk;   dst = WkT;   K = CC_; break;
    case 2: src = Wv;   dst = WvT;   K = CC_; break;
    case 3: src = Wkip; dst = WkipT; K = CC_; break;
    case 4: src = Wvip; dst = WvipT; K = CC_; break;
    default:src = Wout; dst = WoutT; K = C_;  break;
  }
  const int tileK = blockIdx.x / 40;
  const int tileN = blockIdx.x % 40;
  if (tileK >= (K >> 5)) return;
  __shared__ float tile[32][33];
  const int tx = threadIdx.x & 31, ty = threadIdx.x >> 5;
  const int k0 = tileK*32, n0 = tileN*32;
  #pragma unroll
  for (int r = 0; r < 32; r += 8)
    tile[ty + r][tx] = src[(size_t)(k0 + ty + r)*C_ + n0 + tx];
  __syncthreads();
  #pragma unroll
  for (int r = 0; r < 32; r += 8) {
    const int n = n0 + ty + r, k = k0 + tx;
    dst[(size_t)n*K + k] = f2bf(tile[tx][ty + r]);
  }
}

// ---------------- MFMA bf16 GEMM core (dbuf LDS + XOR slot swizzle) ----------------
// C[M,1280] = A[M,K] * BT[1280,K]^T. 128x128 tile, BK=64, 4 waves (2x2).
// LDS tiles are [128 rows][8 slots of 16B]; logical slot s of row r lives at
// physical slot s ^ (r&7). global_load_lds writes linearly, so the global
// SOURCE address is pre-swizzled (rule #21); ds_reads apply the same XOR.
// Double-buffered: stage(k+1) issued BEFORE compute(k); one barrier per step.
template<int MODE, typename OutT>
__device__ __forceinline__ void gemm_core(
    const u16* __restrict__ A, int lda, int M,
    const u16* __restrict__ BT, int K,
    OutT* __restrict__ Cm,
    const float* __restrict__ bias, const float* __restrict__ resid,
    int mt, int nt) {
  __shared__ u16 As0[128*64];
  __shared__ u16 Bs0[128*64];
  __shared__ u16 As1[128*64];
  __shared__ u16 Bs1[128*64];
  const int tid  = threadIdx.x;
  const int lane = tid & 63, wave = tid >> 6;
  const int wm = wave >> 1, wn = wave & 1;
  const int lhi = lane >> 4, llo = lane & 15;
  const int lsw = llo & 7;                 // row-XOR term for reads

  f32x4 acc[4][4] = {};

  auto stage = [&](int kt, u16* As, u16* Bs) {
    #pragma unroll
    for (int it = 0; it < 4; ++it) {
      const int chunk = it*256 + tid;      // 1024 x 16B chunks per tile
      const int r  = chunk >> 3;           // row 0..127
      const int c8 = chunk & 7;            // physical LDS slot
      const int g8 = c8 ^ (r & 7);         // global slot landing here
      int row_g = mt*128 + r; row_g = (row_g < M) ? row_g : (M - 1);
      gload16(A  + (size_t)row_g*lda + kt*64 + g8*8, As + (size_t)(it*256 + wave*64)*8);
      const int nrow = nt*128 + r;         // N=1280 exact
      gload16(BT + (size_t)nrow*K  + kt*64 + g8*8, Bs + (size_t)(it*256 + wave*64)*8);
    }
  };

  auto compute = [&](const u16* As, const u16* Bs) {
    #pragma unroll
    for (int ks = 0; ks < 2; ++ks) {
      bf16x8 av[4], bv[4];
      #pragma unroll
      for (int mm = 0; mm < 4; ++mm) {
        const int row = wm*64 + mm*16 + llo;
        av[mm] = *(const bf16x8*)(As + row*64 + (((ks*4 + lhi) ^ lsw) << 3));
      }
      #pragma unroll
      for (int nn = 0; nn < 4; ++nn) {
        const int row = wn*64 + nn*16 + llo;
        bv[nn] = *(const bf16x8*)(Bs + row*64 + (((ks*4 + lhi) ^ lsw) << 3));
      }
      #pragma unroll
      for (int mm = 0; mm < 4; ++mm)
        #pragma unroll
        for (int nn = 0; nn < 4; ++nn)
          acc[mm][nn] = __builtin_amdgcn_mfma_f32_16x16x32_bf16(av[mm], bv[nn], acc[mm][nn], 0, 0, 0);
    }
  };

  const int nkt = K >> 6;
  stage(0, As0, Bs0);
  __syncthreads();                         // drain prologue loads
  for (int kt = 0; kt < nkt; kt += 2) {
    if (kt + 1 < nkt) stage(kt + 1, As1, Bs1);   // issue-early
    compute(As0, Bs0);
    __syncthreads();                       // vmcnt(0): buf1 ready; buf0 free
    if (kt + 2 < nkt) stage(kt + 2, As0, Bs0);
    if (kt + 1 < nkt) compute(As1, Bs1);
    __syncthreads();
  }

  #pragma unroll
  for (int mm = 0; mm < 4; ++mm) {
    #pragma unroll
    for (int nn = 0; nn < 4; ++nn) {
      const int row0 = mt*128 + wm*64 + mm*16 + lhi*4;
      const int col  = nt*128 + wn*64 + nn*16 + llo;
      #pragma unroll
      for (int r = 0; r < 4; ++r) {
        const int row = row0 + r;
        if (row < M) {
          float v = acc[mm][nn][r];
          if constexpr (MODE == 1) {
            v += bias[col] + resid[(size_t)row*C_ + col];
            Cm[(size_t)row*C_ + col] = v;
          } else {
            Cm[(size_t)row*C_ + col] = f2bf(v);
          }
        }
      }
    }
  }
}

template<int MODE, typename OutT>
__global__ __launch_bounds__(256, 2) void gemm_bf16(
    const u16* __restrict__ A, int lda, int M, const u16* __restrict__ BT, int K,
    OutT* __restrict__ Cm, const float* __restrict__ bias, const float* __restrict__ resid) {
  // XCD chunk swizzle (bijective since gridDim.x % 8 == 0): each XCD gets a
  // contiguous tile chunk -> B panel + neighboring A panels stay in its L2.
  const int nwg = gridDim.x;
  const int bid = blockIdx.x;
  const int swz = (nwg & 7) ? bid : ((bid & 7) * (nwg >> 3) + (bid >> 3));
  gemm_core<MODE, OutT>(A, lda, M, BT, K, Cm, bias, resid, swz / 10, swz % 10);
}

// z-batched tiny projections -> bf16 outputs
__global__ __launch_bounds__(256, 2) void gemm_small(
    const u16* __restrict__ encbf, const u16* __restrict__ ipbf,
    const u16* __restrict__ WkT, const u16* __restrict__ WvT,
    const u16* __restrict__ WkipT, const u16* __restrict__ WvipT,
    u16* __restrict__ Kbf, u16* __restrict__ Vbf,
    u16* __restrict__ Kipbf, u16* __restrict__ Vipbf) {
  const int z = blockIdx.y;
  const u16* A; const u16* BT; u16* Cm; int M;
  if      (z == 0) { A = encbf; BT = WkT;   Cm = Kbf;   M = B_*S_; }
  else if (z == 1) { A = encbf; BT = WvT;   Cm = Vbf;   M = B_*S_; }
  else if (z == 2) { A = ipbf;  BT = WkipT; Cm = Kipbf; M = B_*TIP_; }
  else             { A = ipbf;  BT = WvipT; Cm = Vipbf; M = B_*TIP_; }
  gemm_core<2, u16>(A, CC_, M, BT, CC_, Cm, nullptr, nullptr, blockIdx.x / 10, blockIdx.x % 10);
}

// ---------------- MFMA fused attention ----------------
// Unified key space of 96: [0,77)=text keys, [77,80)=zero pad, [80,96)=IP keys.
#define KSP   96          // padded key space
#define KLD   72          // K LDS stride (2-way bank alias only)
#define PLD   104         // P / Vt LDS stride (2-way bank alias only)
__global__ __launch_bounds__(256) void attn_mfma(
    const u16* __restrict__ Qbf,
    const u16* __restrict__ Kbf,  const u16* __restrict__ Vbf,
    const u16* __restrict__ Kipbf, const u16* __restrict__ Vipbf,
    const float* __restrict__ region, const float* __restrict__ sigma,
    u16* __restrict__ attnbf) {
  __shared__ u16 Kl[KSP*KLD];       // K rows (keys) x 64 dims, stride 72
  __shared__ u16 Vt[64*PLD];        // V transposed: [d][s], stride 104
  __shared__ u16 Pl[4*32*PLD];      // per-wave P tiles [32 rows][96 cols], stride 104
  const int b = blockIdx.z, h = blockIdx.y;
  const int tid = threadIdx.x, lane = tid & 63, wave = tid >> 6;
  const int llo = lane & 15, lhi = lane >> 4;

  for (int i = tid; i < KSP*8; i += 256) {
    const int r = i >> 3, c8 = i & 7;
    u16x8 val = {0,0,0,0,0,0,0,0};
    if (r < S_)
      val = *(const u16x8*)(Kbf + ((size_t)(b*S_ + r))*C_ + h*64 + c8*8);
    else if (r >= 80)
      val = *(const u16x8*)(Kipbf + ((size_t)(b*TIP_ + r - 80))*C_ + h*64 + c8*8);
    *(u16x8*)(Kl + r*KLD + c8*8) = val;
  }
  for (int i = tid; i < KSP*64; i += 256) {
    const int s = i >> 6, d = i & 63;
    u16 val = 0;
    if (s < S_)       val = Vbf[((size_t)(b*S_ + s))*C_ + h*64 + d];
    else if (s >= 80) val = Vipbf[((size_t)(b*TIP_ + s - 80))*C_ + h*64 + d];
    Vt[d*PLD + s] = val;
  }
  __syncthreads();

  const int row0 = blockIdx.x*128 + wave*32;

  bf16x8 av[2][2];
  #pragma unroll
  for (int mm = 0; mm < 2; ++mm)
    #pragma unroll
    for (int ks = 0; ks < 2; ++ks)
      av[mm][ks] = *(const bf16x8*)(Qbf + ((size_t)(b*L_ + row0 + mm*16 + llo))*C_ + h*64 + ks*32 + lhi*8);

  f32x4 acc[2][6] = {};
  #pragma unroll
  for (int ks = 0; ks < 2; ++ks) {
    bf16x8 bv[6];
    #pragma unroll
    for (int nn = 0; nn < 6; ++nn)
      bv[nn] = *(const bf16x8*)(Kl + (nn*16 + llo)*KLD + ks*32 + lhi*8);
    #pragma unroll
    for (int mm = 0; mm < 2; ++mm)
      #pragma unroll
      for (int nn = 0; nn < 6; ++nn)
        acc[mm][nn] = __builtin_amdgcn_mfma_f32_16x16x32_bf16(av[mm][ks], bv[nn], acc[mm][nn], 0, 0, 0);
  }

  const float sigscale = sigma[0] * 0.3f;   // REGION_WEIGHT
  const float scale = 0.125f;               // 1/sqrt(64)
  u16* Pw = Pl + wave*32*PLD;

  #pragma unroll
  for (int mm = 0; mm < 2; ++mm) {
    const int rowbase = b*L_ + row0 + mm*16 + lhi*4;
    float sc[5][4];
    float mx[4] = {-1e30f, -1e30f, -1e30f, -1e30f};
    #pragma unroll
    for (int nn = 0; nn < 5; ++nn) {
      const int col = nn*16 + llo;
      #pragma unroll
      for (int r = 0; r < 4; ++r) {
        float v = -1e30f;
        if (col < S_) {
          const float bias = region[((size_t)(rowbase + r))*S_ + col] * sigscale;
          v = fmaf(acc[mm][nn][r], scale, bias);
        }
        sc[nn][r] = v;
        mx[r] = fmaxf(mx[r], v);
      }
    }
    #pragma unroll
    for (int st = 1; st < 16; st <<= 1)
      #pragma unroll
      for (int r = 0; r < 4; ++r)
        mx[r] = fmaxf(mx[r], __shfl_xor(mx[r], st));
    float sum[4] = {0.f, 0.f, 0.f, 0.f};
    #pragma unroll
    for (int nn = 0; nn < 5; ++nn)
      #pragma unroll
      for (int r = 0; r < 4; ++r) {
        const float e = __expf(sc[nn][r] - mx[r]);
        sc[nn][r] = e; sum[r] += e;
      }
    #pragma unroll
    for (int st = 1; st < 16; st <<= 1)
      #pragma unroll
      for (int r = 0; r < 4; ++r)
        sum[r] += __shfl_xor(sum[r], st);
    float inv[4];
    #pragma unroll
    for (int r = 0; r < 4; ++r) inv[r] = 1.f / sum[r];

    float ipe[4], mi[4], sumi[4];
    #pragma unroll
    for (int r = 0; r < 4; ++r) { ipe[r] = acc[mm][5][r] * scale; mi[r] = ipe[r]; }
    #pragma unroll
    for (int st = 1; st < 16; st <<= 1)
      #pragma unroll
      for (int r = 0; r < 4; ++r)
        mi[r] = fmaxf(mi[r], __shfl_xor(mi[r], st));
    #pragma unroll
    for (int r = 0; r < 4; ++r) { ipe[r] = __expf(ipe[r] - mi[r]); sumi[r] = ipe[r]; }
    #pragma unroll
    for (int st = 1; st < 16; st <<= 1)
      #pragma unroll
      for (int r = 0; r < 4; ++r)
        sumi[r] += __shfl_xor(sumi[r], st);

    #pragma unroll
    for (int nn = 0; nn < 5; ++nn)
      #pragma unroll
      for (int r = 0; r < 4; ++r)
        Pw[(mm*16 + lhi*4 + r)*PLD + nn*16 + llo] = f2bf(sc[nn][r] * inv[r]);
    #pragma unroll
    for (int r = 0; r < 4; ++r)
      Pw[(mm*16 + lhi*4 + r)*PLD + 80 + llo] = f2bf(ipe[r] / sumi[r]);
  }

  f32x4 oacc[2][4] = {};
  #pragma unroll
  for (int ks = 0; ks < 3; ++ks) {
    bf16x8 pa[2], vv[4];
    #pragma unroll
    for (int mm = 0; mm < 2; ++mm)
      pa[mm] = *(const bf16x8*)(Pw + (mm*16 + llo)*PLD + ks*32 + lhi*8);
    #pragma unroll
    for (int nn = 0; nn < 4; ++nn)
      vv[nn] = *(const bf16x8*)(Vt + (nn*16 + llo)*PLD + ks*32 + lhi*8);
    #pragma unroll
    for (int mm = 0; mm < 2; ++mm)
      #pragma unroll
      for (int nn = 0; nn < 4; ++nn)
        oacc[mm][nn] = __builtin_amdgcn_mfma_f32_16x16x32_bf16(pa[mm], vv[nn], oacc[mm][nn], 0, 0, 0);
  }

  #pragma unroll
  for (int mm = 0; mm < 2; ++mm)
    #pragma unroll
    for (int nn = 0; nn < 4; ++nn)
      #pragma unroll
      for (int r = 0; r < 4; ++r) {
        const int grow = row0 + mm*16 + lhi*4 + r;
        attnbf[((size_t)(b*L_ + grow))*C_ + h*64 + nn*16 + llo] = f2bf(oacc[mm][nn][r]);
      }
}

// ---------------- launcher ----------------
extern "C" void kernel_launch(void* const* d_in, const int* in_sizes, int n_in,
                              void* d_out, int out_size, void* d_ws, size_t ws_size,
                              hipStream_t stream) {
  const float* hidden = (const float*)d_in[0];
  const float* enc    = (const float*)d_in[1];
  const float* ip     = (const float*)d_in[2];
  const float* region = (const float*)d_in[3];
  const float* sigma  = (const float*)d_in[4];
  const float* Wq     = (const float*)d_in[5];
  const float* Wk     = (const float*)d_in[6];
  const float* Wv     = (const float*)d_in[7];
  const float* Wkip   = (const float*)d_in[8];
  const float* Wvip   = (const float*)d_in[9];
  const float* Wout   = (const float*)d_in[10];
  const float* bout   = (const float*)d_in[11];

  char* base = (char*)d_ws;
  size_t off = 0;
  auto carve = [&](size_t bytes) -> void* {
    void* r = base + off;
    off += (bytes + 255) & ~(size_t)255;
    return r;
  };
  u16* Xbf    = (u16*)carve((size_t)B_*L_*C_*2);
  u16* encbf  = (u16*)carve((size_t)B_*S_*CC_*2);
  u16* ipbf   = (u16*)carve((size_t)B_*TIP_*CC_*2);
  u16* WqT    = (u16*)carve((size_t)C_*C_*2);
  u16* WkT    = (u16*)carve((size_t)C_*CC_*2);
  u16* WvT    = (u16*)carve((size_t)C_*CC_*2);
  u16* WkipT  = (u16*)carve((size_t)C_*CC_*2);
  u16* WvipT  = (u16*)carve((size_t)C_*CC_*2);
  u16* WoutT  = (u16*)carve((size_t)C_*C_*2);
  u16* Qbf    = (u16*)carve((size_t)B_*L_*C_*2);
  u16* Kbf    = (u16*)carve((size_t)B_*S_*C_*2);
  u16* Vbf    = (u16*)carve((size_t)B_*S_*C_*2);
  u16* Kipbf  = (u16*)carve((size_t)B_*TIP_*C_*2);
  u16* Vipbf  = (u16*)carve((size_t)B_*TIP_*C_*2);
  u16* attnbf = (u16*)carve((size_t)B_*L_*C_*2);
  (void)ws_size; (void)in_sizes; (void)n_in; (void)out_size;

  prep_cast<<<2048, 256, 0, stream>>>(hidden, enc, ip, Xbf, encbf, ipbf);
  transpose_cast<<<dim3(1600, 6), 256, 0, stream>>>(Wq, Wk, Wv, Wkip, Wvip, Wout,
                                                    WqT, WkT, WvT, WkipT, WvipT, WoutT);
  // Q = X @ Wq -> bf16
  gemm_bf16<2, u16><<<dim3(64*10), 256, 0, stream>>>(Xbf, C_, B_*L_, WqT, C_, Qbf, nullptr, nullptr);
  // K,V,K_ip,V_ip projections -> bf16
  gemm_small<<<dim3(2*10, 4), 256, 0, stream>>>(encbf, ipbf, WkT, WvT, WkipT, WvipT,
                                                Kbf, Vbf, Kipbf, Vipbf);
  // fused MFMA attention (text + IP) -> bf16
  attn_mfma<<<dim3(L_/128, H_, B_), 256, 0, stream>>>(Qbf, Kbf, Vbf, Kipbf, Vipbf,
                                                      region, sigma, attnbf);
  // out = attn @ Wout + b_out + residual
  gemm_bf16<1, float><<<dim3(64*10), 256, 0, stream>>>(attnbf, C_, B_*L_, WoutT, C_,
                                                       (float*)d_out, bout, hidden);
}

// Round 4
// 150.755 us; speedup vs baseline: 3.2410x; 1.1917x over previous
//
#include <hip/hip_runtime.h>
#include <cstdint>
#include <cstddef>

#define B_   2
#define L_   4096
#define S_   77
#define TIP_ 16
#define C_   1280
#define CC_  768
#define H_   20

typedef unsigned short u16;
typedef unsigned int   u32;
typedef __attribute__((ext_vector_type(8))) short bf16x8;
typedef __attribute__((ext_vector_type(8))) unsigned short u16x8;
typedef __attribute__((ext_vector_type(4))) float f32x4;

// f32 -> bf16 round-to-nearest-even
__device__ __forceinline__ u16 f2bf(float x) {
  u32 u = __float_as_uint(x);
  u32 r = (u + 0x7fffu + ((u >> 16) & 1u)) >> 16;
  return (u16)r;
}

// async global->LDS, 16B per lane (dest = wave-uniform base + lane*16)
__device__ __forceinline__ void gload16(const u16* g, const u16* l) {
  __builtin_amdgcn_global_load_lds(
      (const __attribute__((address_space(1))) u32*)g,
      (__attribute__((address_space(3))) u32*)(uintptr_t)l, 16, 0, 0);
}

// raw barrier: NO implicit vmcnt(0) drain (unlike __syncthreads)
__device__ __forceinline__ void wg_barrier() {
  asm volatile("s_barrier" ::: "memory");
}
template<int N>
__device__ __forceinline__ void vm_wait() {
  asm volatile("s_waitcnt vmcnt(%0)" :: "i"(N) : "memory");
}

// ---------------- prep: flat f32->bf16 casts (X, enc, ip) ----------------
__global__ __launch_bounds__(256) void prep_cast(
    const float* __restrict__ X, const float* __restrict__ enc, const float* __restrict__ ip,
    u16* __restrict__ Xbf, u16* __restrict__ encbf, u16* __restrict__ ipbf) {
  const int nX = B_*L_*C_;
  const int nE = B_*S_*CC_;
  const int nI = B_*TIP_*CC_;
  const int total4 = (nX + nE + nI) >> 2;
  for (int i = blockIdx.x*256 + threadIdx.x; i < total4; i += gridDim.x*256) {
    int idx = i << 2;
    const float* src; u16* dst; int off;
    if (idx < nX)            { src = X;   dst = Xbf;   off = idx; }
    else if (idx < nX + nE)  { src = enc; dst = encbf; off = idx - nX; }
    else                     { src = ip;  dst = ipbf;  off = idx - nX - nE; }
    float4 v = *(const float4*)(src + off);
    ushort4 o;
    o.x = f2bf(v.x); o.y = f2bf(v.y); o.z = f2bf(v.z); o.w = f2bf(v.w);
    *(ushort4*)(dst + off) = o;
  }
}

// ---------------- transpose-cast: W [K][1280] f32 -> WT [1280][K] bf16 ----------------
__global__ __launch_bounds__(256) void transpose_cast(
    const float* __restrict__ Wq,  const float* __restrict__ Wk,   const float* __restrict__ Wv,
    const float* __restrict__ Wkip,const float* __restrict__ Wvip, const float* __restrict__ Wout,
    u16* __restrict__ WqT, u16* __restrict__ WkT, u16* __restrict__ WvT,
    u16* __restrict__ WkipT, u16* __restrict__ WvipT, u16* __restrict__ WoutT) {
  const int m = blockIdx.y;
  const float* src; u16* dst; int K;
  switch (m) {
    case 0: src = Wq;   dst = WqT;   K = C_;  break;
    case 1: src = Wk;   dst = WkT;   K = CC_; break;
    case 2: src = Wv;   dst = WvT;   K = CC_; break;
    case 3: src = Wkip; dst = WkipT; K = CC_; break;
    case 4: src = Wvip; dst = WvipT; K = CC_; break;
    default:src = Wout; dst = WoutT; K = C_;  break;
  }
  const int tileK = blockIdx.x / 40;
  const int tileN = blockIdx.x % 40;
  if (tileK >= (K >> 5)) return;
  __shared__ float tile[32][33];
  const int tx = threadIdx.x & 31, ty = threadIdx.x >> 5;
  const int k0 = tileK*32, n0 = tileN*32;
  #pragma unroll
  for (int r = 0; r < 32; r += 8)
    tile[ty + r][tx] = src[(size_t)(k0 + ty + r)*C_ + n0 + tx];
  __syncthreads();
  #pragma unroll
  for (int r = 0; r < 32; r += 8) {
    const int n = n0 + ty + r, k = k0 + tx;
    dst[(size_t)n*K + k] = f2bf(tile[tx][ty + r]);
  }
}

// ---------------- MFMA bf16 GEMM core (counted-vmcnt depth-2 pipeline) ----------------
// C[M,N] = A[M,K] * BT[N,K]^T. BM=128 x BN tile, BK=64, 4 waves (2x2).
// LDS slot-XOR swizzle (physical slot = logical ^ (row&7)), applied via
// pre-swizzled GLOBAL source + swizzled ds_read (rule #21).
// Depth-2 pipeline with raw s_barrier + counted vmcnt: the __syncthreads
// vmcnt(0) drain was the 4400cy/step stall (m97-structure ceiling).
template<int BN, int MODE, typename OutT>
__device__ __forceinline__ void gemm_core(
    const u16* __restrict__ A, int lda, int M,
    const u16* __restrict__ BT, int K,
    OutT* __restrict__ Cm,
    const float* __restrict__ bias, const float* __restrict__ resid,
    int mt, int nt) {
  constexpr int NF  = BN / 32;          // n-frags per wave (wave covers BN/2 cols)
  constexpr int BCH = BN / 32;          // B 16B-chunks per thread per stage
  constexpr int LP  = 4 + BCH;          // loads per thread per stage
  __shared__ u16 As0[128*64];
  __shared__ u16 Bs0[BN*64];
  __shared__ u16 As1[128*64];
  __shared__ u16 Bs1[BN*64];
  const int tid  = threadIdx.x;
  const int lane = tid & 63, wave = tid >> 6;
  const int wm = wave >> 1, wn = wave & 1;
  const int lhi = lane >> 4, llo = lane & 15;
  const int lsw = llo & 7;              // row-XOR term for fragment reads

  f32x4 acc[4][NF] = {};

  auto stage = [&](int kt, u16* As, u16* Bs) {
    #pragma unroll
    for (int it = 0; it < 4; ++it) {
      const int chunk = it*256 + wave*64 + lane;   // per-lane chunk id
      const int r  = chunk >> 3;
      const int c8 = chunk & 7;
      const int g8 = c8 ^ (r & 7);                 // pre-swizzled global slot
      int row_g = mt*128 + r; row_g = (row_g < M) ? row_g : (M - 1);
      gload16(A + (size_t)row_g*lda + kt*64 + g8*8,
              As + (size_t)(it*256 + wave*64)*8);  // wave-uniform LDS base
    }
    #pragma unroll
    for (int it = 0; it < BCH; ++it) {
      const int chunk = it*256 + wave*64 + lane;
      const int r  = chunk >> 3;
      const int c8 = chunk & 7;
      const int g8 = c8 ^ (r & 7);
      const int nrow = nt*BN + r;                  // N=1280 exact, no clamp
      gload16(BT + (size_t)nrow*K + kt*64 + g8*8,
              Bs + (size_t)(it*256 + wave*64)*8);
    }
  };

  auto compute = [&](const u16* As, const u16* Bs) {
    #pragma unroll
    for (int ks = 0; ks < 2; ++ks) {
      bf16x8 av[4], bv[NF];
      #pragma unroll
      for (int mm = 0; mm < 4; ++mm) {
        const int row = wm*64 + mm*16 + llo;
        av[mm] = *(const bf16x8*)(As + row*64 + (((ks*4 + lhi) ^ lsw) << 3));
      }
      #pragma unroll
      for (int nn = 0; nn < NF; ++nn) {
        const int row = wn*(BN/2) + nn*16 + llo;
        bv[nn] = *(const bf16x8*)(Bs + row*64 + (((ks*4 + lhi) ^ lsw) << 3));
      }
      #pragma unroll
      for (int mm = 0; mm < 4; ++mm)
        #pragma unroll
        for (int nn = 0; nn < NF; ++nn)
          acc[mm][nn] = __builtin_amdgcn_mfma_f32_16x16x32_bf16(av[mm], bv[nn], acc[mm][nn], 0, 0, 0);
    }
  };

  const int nkt = K >> 6;               // 20 or 12, always >= 2
  stage(0, As0, Bs0);
  stage(1, As1, Bs1);
  vm_wait<LP>();                        // buf0's loads (oldest LP) complete
  wg_barrier();
  __builtin_amdgcn_sched_barrier(0);

  for (int kt = 0; kt < nkt; ++kt) {
    u16* As = (kt & 1) ? As1 : As0;
    u16* Bs = (kt & 1) ? Bs1 : Bs0;
    compute(As, Bs);
    if (kt + 2 < nkt) {
      wg_barrier();                     // all waves done reading As/Bs
      stage(kt + 2, As, Bs);            // re-stage the buffer just consumed
      vm_wait<LP>();                    // other buffer's loads complete
      wg_barrier();
      __builtin_amdgcn_sched_barrier(0);
    } else if (kt + 1 < nkt) {
      vm_wait<0>();                     // last prefetched buffer: full drain
      wg_barrier();
      __builtin_amdgcn_sched_barrier(0);
    }
  }

  #pragma unroll
  for (int mm = 0; mm < 4; ++mm) {
    #pragma unroll
    for (int nn = 0; nn < NF; ++nn) {
      const int row0 = mt*128 + wm*64 + mm*16 + lhi*4;
      const int col  = nt*BN + wn*(BN/2) + nn*16 + llo;
      #pragma unroll
      for (int r = 0; r < 4; ++r) {
        const int row = row0 + r;
        if (row < M) {
          float v = acc[mm][nn][r];
          if constexpr (MODE == 1) {
            v += bias[col] + resid[(size_t)row*C_ + col];
            Cm[(size_t)row*C_ + col] = v;
          } else {
            Cm[(size_t)row*C_ + col] = f2bf(v);
          }
        }
      }
    }
  }
}

// big GEMMs: BN=160 -> grid 64 x 8 = 512 blocks = exactly 2/CU (no tail round)
template<int MODE, typename OutT>
__global__ __launch_bounds__(256, 2) void gemm_bf16(
    const u16* __restrict__ A, int lda, int M, const u16* __restrict__ BT, int K,
    OutT* __restrict__ Cm, const float* __restrict__ bias, const float* __restrict__ resid) {
  const int nwg = gridDim.x;            // 512, %8==0 -> bijective XCD swizzle
  const int bid = blockIdx.x;
  const int swz = (nwg & 7) ? bid : ((bid & 7) * (nwg >> 3) + (bid >> 3));
  gemm_core<160, MODE, OutT>(A, lda, M, BT, K, Cm, bias, resid, swz >> 3, swz & 7);
}

// z-batched tiny projections -> bf16 outputs (BN=128 geometry)
__global__ __launch_bounds__(256, 2) void gemm_small(
    const u16* __restrict__ encbf, const u16* __restrict__ ipbf,
    const u16* __restrict__ WkT, const u16* __restrict__ WvT,
    const u16* __restrict__ WkipT, const u16* __restrict__ WvipT,
    u16* __restrict__ Kbf, u16* __restrict__ Vbf,
    u16* __restrict__ Kipbf, u16* __restrict__ Vipbf) {
  const int z = blockIdx.y;
  const u16* A; const u16* BT; u16* Cm; int M;
  if      (z == 0) { A = encbf; BT = WkT;   Cm = Kbf;   M = B_*S_; }
  else if (z == 1) { A = encbf; BT = WvT;   Cm = Vbf;   M = B_*S_; }
  else if (z == 2) { A = ipbf;  BT = WkipT; Cm = Kipbf; M = B_*TIP_; }
  else             { A = ipbf;  BT = WvipT; Cm = Vipbf; M = B_*TIP_; }
  gemm_core<128, 2, u16>(A, CC_, M, BT, CC_, Cm, nullptr, nullptr, blockIdx.x / 10, blockIdx.x % 10);
}

// ---------------- MFMA fused attention ----------------
// Unified key space of 96: [0,77)=text keys, [77,80)=zero pad, [80,96)=IP keys.
#define KSP   96          // padded key space
#define KLD   72          // K LDS stride (2-way bank alias only)
#define PLD   104         // P / Vt LDS stride (2-way bank alias only)
__global__ __launch_bounds__(256) void attn_mfma(
    const u16* __restrict__ Qbf,
    const u16* __restrict__ Kbf,  const u16* __restrict__ Vbf,
    const u16* __restrict__ Kipbf, const u16* __restrict__ Vipbf,
    const float* __restrict__ region, const float* __restrict__ sigma,
    u16* __restrict__ attnbf) {
  __shared__ u16 Kl[KSP*KLD];
  __shared__ u16 Vt[64*PLD];
  __shared__ u16 Pl[4*32*PLD];
  const int b = blockIdx.z, h = blockIdx.y;
  const int tid = threadIdx.x, lane = tid & 63, wave = tid >> 6;
  const int llo = lane & 15, lhi = lane >> 4;

  for (int i = tid; i < KSP*8; i += 256) {
    const int r = i >> 3, c8 = i & 7;
    u16x8 val = {0,0,0,0,0,0,0,0};
    if (r < S_)
      val = *(const u16x8*)(Kbf + ((size_t)(b*S_ + r))*C_ + h*64 + c8*8);
    else if (r >= 80)
      val = *(const u16x8*)(Kipbf + ((size_t)(b*TIP_ + r - 80))*C_ + h*64 + c8*8);
    *(u16x8*)(Kl + r*KLD + c8*8) = val;
  }
  for (int i = tid; i < KSP*64; i += 256) {
    const int s = i >> 6, d = i & 63;
    u16 val = 0;
    if (s < S_)       val = Vbf[((size_t)(b*S_ + s))*C_ + h*64 + d];
    else if (s >= 80) val = Vipbf[((size_t)(b*TIP_ + s - 80))*C_ + h*64 + d];
    Vt[d*PLD + s] = val;
  }
  __syncthreads();

  const int row0 = blockIdx.x*128 + wave*32;

  bf16x8 av[2][2];
  #pragma unroll
  for (int mm = 0; mm < 2; ++mm)
    #pragma unroll
    for (int ks = 0; ks < 2; ++ks)
      av[mm][ks] = *(const bf16x8*)(Qbf + ((size_t)(b*L_ + row0 + mm*16 + llo))*C_ + h*64 + ks*32 + lhi*8);

  f32x4 acc[2][6] = {};
  #pragma unroll
  for (int ks = 0; ks < 2; ++ks) {
    bf16x8 bv[6];
    #pragma unroll
    for (int nn = 0; nn < 6; ++nn)
      bv[nn] = *(const bf16x8*)(Kl + (nn*16 + llo)*KLD + ks*32 + lhi*8);
    #pragma unroll
    for (int mm = 0; mm < 2; ++mm)
      #pragma unroll
      for (int nn = 0; nn < 6; ++nn)
        acc[mm][nn] = __builtin_amdgcn_mfma_f32_16x16x32_bf16(av[mm][ks], bv[nn], acc[mm][nn], 0, 0, 0);
  }

  const float sigscale = sigma[0] * 0.3f;   // REGION_WEIGHT
  const float scale = 0.125f;               // 1/sqrt(64)
  u16* Pw = Pl + wave*32*PLD;

  #pragma unroll
  for (int mm = 0; mm < 2; ++mm) {
    const int rowbase = b*L_ + row0 + mm*16 + lhi*4;
    float sc[5][4];
    float mx[4] = {-1e30f, -1e30f, -1e30f, -1e30f};
    #pragma unroll
    for (int nn = 0; nn < 5; ++nn) {
      const int col = nn*16 + llo;
      #pragma unroll
      for (int r = 0; r < 4; ++r) {
        float v = -1e30f;
        if (col < S_) {
          const float bias = region[((size_t)(rowbase + r))*S_ + col] * sigscale;
          v = fmaf(acc[mm][nn][r], scale, bias);
        }
        sc[nn][r] = v;
        mx[r] = fmaxf(mx[r], v);
      }
    }
    #pragma unroll
    for (int st = 1; st < 16; st <<= 1)
      #pragma unroll
      for (int r = 0; r < 4; ++r)
        mx[r] = fmaxf(mx[r], __shfl_xor(mx[r], st));
    float sum[4] = {0.f, 0.f, 0.f, 0.f};
    #pragma unroll
    for (int nn = 0; nn < 5; ++nn)
      #pragma unroll
      for (int r = 0; r < 4; ++r) {
        const float e = __expf(sc[nn][r] - mx[r]);
        sc[nn][r] = e; sum[r] += e;
      }
    #pragma unroll
    for (int st = 1; st < 16; st <<= 1)
      #pragma unroll
      for (int r = 0; r < 4; ++r)
        sum[r] += __shfl_xor(sum[r], st);
    float inv[4];
    #pragma unroll
    for (int r = 0; r < 4; ++r) inv[r] = 1.f / sum[r];

    float ipe[4], mi[4], sumi[4];
    #pragma unroll
    for (int r = 0; r < 4; ++r) { ipe[r] = acc[mm][5][r] * scale; mi[r] = ipe[r]; }
    #pragma unroll
    for (int st = 1; st < 16; st <<= 1)
      #pragma unroll
      for (int r = 0; r < 4; ++r)
        mi[r] = fmaxf(mi[r], __shfl_xor(mi[r], st));
    #pragma unroll
    for (int r = 0; r < 4; ++r) { ipe[r] = __expf(ipe[r] - mi[r]); sumi[r] = ipe[r]; }
    #pragma unroll
    for (int st = 1; st < 16; st <<= 1)
      #pragma unroll
      for (int r = 0; r < 4; ++r)
        sumi[r] += __shfl_xor(sumi[r], st);

    #pragma unroll
    for (int nn = 0; nn < 5; ++nn)
      #pragma unroll
      for (int r = 0; r < 4; ++r)
        Pw[(mm*16 + lhi*4 + r)*PLD + nn*16 + llo] = f2bf(sc[nn][r] * inv[r]);
    #pragma unroll
    for (int r = 0; r < 4; ++r)
      Pw[(mm*16 + lhi*4 + r)*PLD + 80 + llo] = f2bf(ipe[r] / sumi[r]);
  }

  f32x4 oacc[2][4] = {};
  #pragma unroll
  for (int ks = 0; ks < 3; ++ks) {
    bf16x8 pa[2], vv[4];
    #pragma unroll
    for (int mm = 0; mm < 2; ++mm)
      pa[mm] = *(const bf16x8*)(Pw + (mm*16 + llo)*PLD + ks*32 + lhi*8);
    #pragma unroll
    for (int nn = 0; nn < 4; ++nn)
      vv[nn] = *(const bf16x8*)(Vt + (nn*16 + llo)*PLD + ks*32 + lhi*8);
    #pragma unroll
    for (int mm = 0; mm < 2; ++mm)
      #pragma unroll
      for (int nn = 0; nn < 4; ++nn)
        oacc[mm][nn] = __builtin_amdgcn_mfma_f32_16x16x32_bf16(pa[mm], vv[nn], oacc[mm][nn], 0, 0, 0);
  }

  #pragma unroll
  for (int mm = 0; mm < 2; ++mm)
    #pragma unroll
    for (int nn = 0; nn < 4; ++nn)
      #pragma unroll
      for (int r = 0; r < 4; ++r) {
        const int grow = row0 + mm*16 + lhi*4 + r;
        attnbf[((size_t)(b*L_ + grow))*C_ + h*64 + nn*16 + llo] = f2bf(oacc[mm][nn][r]);
      }
}

// ---------------- launcher ----------------
extern "C" void kernel_launch(void* const* d_in, const int* in_sizes, int n_in,
                              void* d_out, int out_size, void* d_ws, size_t ws_size,
                              hipStream_t stream) {
  const float* hidden = (const float*)d_in[0];
  const float* enc    = (const float*)d_in[1];
  const float* ip     = (const float*)d_in[2];
  const float* region = (const float*)d_in[3];
  const float* sigma  = (const float*)d_in[4];
  const float* Wq     = (const float*)d_in[5];
  const float* Wk     = (const float*)d_in[6];
  const float* Wv     = (const float*)d_in[7];
  const float* Wkip   = (const float*)d_in[8];
  const float* Wvip   = (const float*)d_in[9];
  const float* Wout   = (const float*)d_in[10];
  const float* bout   = (const float*)d_in[11];

  char* base = (char*)d_ws;
  size_t off = 0;
  auto carve = [&](size_t bytes) -> void* {
    void* r = base + off;
    off += (bytes + 255) & ~(size_t)255;
    return r;
  };
  u16* Xbf    = (u16*)carve((size_t)B_*L_*C_*2);
  u16* encbf  = (u16*)carve((size_t)B_*S_*CC_*2);
  u16* ipbf   = (u16*)carve((size_t)B_*TIP_*CC_*2);
  u16* WqT    = (u16*)carve((size_t)C_*C_*2);
  u16* WkT    = (u16*)carve((size_t)C_*CC_*2);
  u16* WvT    = (u16*)carve((size_t)C_*CC_*2);
  u16* WkipT  = (u16*)carve((size_t)C_*CC_*2);
  u16* WvipT  = (u16*)carve((size_t)C_*CC_*2);
  u16* WoutT  = (u16*)carve((size_t)C_*C_*2);
  u16* Qbf    = (u16*)carve((size_t)B_*L_*C_*2);
  u16* Kbf    = (u16*)carve((size_t)B_*S_*C_*2);
  u16* Vbf    = (u16*)carve((size_t)B_*S_*C_*2);
  u16* Kipbf  = (u16*)carve((size_t)B_*TIP_*C_*2);
  u16* Vipbf  = (u16*)carve((size_t)B_*TIP_*C_*2);
  u16* attnbf = (u16*)carve((size_t)B_*L_*C_*2);
  (void)ws_size; (void)in_sizes; (void)n_in; (void)out_size;

  prep_cast<<<2048, 256, 0, stream>>>(hidden, enc, ip, Xbf, encbf, ipbf);
  transpose_cast<<<dim3(1600, 6), 256, 0, stream>>>(Wq, Wk, Wv, Wkip, Wvip, Wout,
                                                    WqT, WkT, WvT, WkipT, WvipT, WoutT);
  // Q = X @ Wq -> bf16   (512 blocks: 64 m-tiles x 8 n-tiles of 160)
  gemm_bf16<2, u16><<<dim3(512), 256, 0, stream>>>(Xbf, C_, B_*L_, WqT, C_, Qbf, nullptr, nullptr);
  // K,V,K_ip,V_ip projections -> bf16
  gemm_small<<<dim3(2*10, 4), 256, 0, stream>>>(encbf, ipbf, WkT, WvT, WkipT, WvipT,
                                                Kbf, Vbf, Kipbf, Vipbf);
  // fused MFMA attention (text + IP) -> bf16
  attn_mfma<<<dim3(L_/128, H_, B_), 256, 0, stream>>>(Qbf, Kbf, Vbf, Kipbf, Vipbf,
                                                      region, sigma, attnbf);
  // out = attn @ Wout + b_out + residual
  gemm_bf16<1, float><<<dim3(512), 256, 0, stream>>>(attnbf, C_, B_*L_, WoutT, C_,
                                                     (float*)d_out, bout, hidden);
}